// Round 4
// baseline (3951.416 us; speedup 1.0000x reference)
//
#include <hip/hip_runtime.h>
#include <hip/hip_bf16.h>

typedef __bf16 bf16x8 __attribute__((ext_vector_type(8)));
typedef float f32x4 __attribute__((ext_vector_type(4)));
typedef unsigned int u32x4 __attribute__((ext_vector_type(4)));
typedef unsigned int u32x2 __attribute__((ext_vector_type(2)));

#define BB   128
#define SS   512
#define DD   128
#define HH   1024
#define OO   64
#define IIN  257

// scan decomposition: 2 batch groups x 64 blocks; each block owns 16 h-cols (64 gate cols)
#define NGROUP 2
#define GBLK   64
#define MG     64     // batch rows per group
#define NC     64     // gate cols per block
#define NT     4      // n-tiles (of 16) per wave
#define KK_H   32     // 1024/32
#define KK_X   9      // 288/32 (257 padded to 288, ti folded in at k=256)

#define XTP_SLAB  18432       // 4mt * 9kk * 64lane * 8 bf16 per (t,p)
#define HBUF_SLAB 65536       // 4mt * 32kk * 64lane * 8 bf16 per (p,buf)
#define WIH_BLK   (NT*KK_X*512)   // 18432 bf16 = 36 KB per block

// ws layout (bytes): [0,1024) flags | [1024, +512K) hbuf (4 slabs)
// | hlast fp32 128x1024 | xtp bf16 1024 slabs | wihp bf16 128 blocks
#define WS_HBUF  1024
#define WS_HLAST 525312
#define WS_XTP   1049600
#define WS_WIHP  38798336     // WS_XTP + 1024*18432*2

// ---- device-scope (sc1) ops: bypass L1/L2, coherent at L3 (MALL). No
// buffer_wbl2/buffer_inv anywhere -> no cache-maintenance serialization.
__device__ __forceinline__ u32x4 ldg_dev16(const void* p) {
  u32x4 r;
  asm volatile("global_load_dwordx4 %0, %1, off sc1" : "=v"(r) : "v"(p));
  return r;
}
__device__ __forceinline__ void stg_dev4(void* p, unsigned int v) {
  asm volatile("global_store_dword %0, %1, off sc1" :: "v"(p), "v"(v));
}
__device__ __forceinline__ void stg_dev8(void* p, u32x2 v) {
  asm volatile("global_store_dwordx2 %0, %1, off sc1" :: "v"(p), "v"(v));
}
__device__ __forceinline__ bf16x8 asbf(u32x4 v) {
  union { u32x4 u; bf16x8 h; } c; c.u = v; return c.h;
}

#define CLAIMW(CNTSTR, A)                                            \
  asm volatile("s_waitcnt vmcnt(" CNTSTR ")"                         \
    : "+v"((A)[0]), "+v"((A)[1]), "+v"((A)[2]), "+v"((A)[3]),        \
      "+v"((A)[4]), "+v"((A)[5]), "+v"((A)[6]), "+v"((A)[7]))

__global__ void prepack_kernel(const float* __restrict__ x, const float* __restrict__ mask,
                               const float* __restrict__ ti, __bf16* __restrict__ xtp) {
  int idx = blockIdx.x * 256 + threadIdx.x;        // 1024 slabs * 18432
  int slab = idx / XTP_SLAB;
  int rem  = idx - slab * XTP_SLAB;
  int p = slab & 1, t = slab >> 1;
  int j = rem & 7, l = (rem >> 3) & 63;
  int t2 = rem >> 9;                               // 0..35
  int kk = t2 % 9, mt = t2 / 9;
  int b = p * MG + mt * 16 + (l & 15);
  int k = kk * 32 + ((l >> 4) << 3) + j;
  float v;
  if (k < 128)       v = x[(b * SS + t) * DD + k];
  else if (k < 256)  v = mask[(b * SS + t) * DD + (k - 128)];
  else if (k == 256) v = ti[b * SS + t];
  else               v = 0.f;
  xtp[idx] = (__bf16)v;
}

// W_ih B-fragments per scan-block: [blk][nt][kk][lane][8]
__global__ void wih_prepack(const float* __restrict__ W_ih, __bf16* __restrict__ wihp) {
  int idx = blockIdx.x * 256 + threadIdx.x;        // 128 * 18432
  int j = idx & 7, l = (idx >> 3) & 63;
  int r = idx >> 9;
  int kk = r % 9; int r2 = r / 9;
  int nt = r2 & 3, blk = r2 >> 2;
  int col = nt * HH + blk * 16 + (l & 15);         // gate=nt, j0=blk*16, jj=l&15
  int k = kk * 32 + ((l >> 4) << 3) + j;
  wihp[idx] = (k < IIN) ? (__bf16)W_ih[col * IIN + k] : (__bf16)0.f;
}

__device__ __forceinline__ float sigmoid_f(float v) { return 1.f / (1.f + __expf(-v)); }
__device__ __forceinline__ float tanh_f(float v)    { return 1.f - 2.f / (__expf(2.f * v) + 1.f); }

__launch_bounds__(256, 1)
__global__ void lstm_scan(const float* __restrict__ W_hh,
                          const float* __restrict__ b_ih, const float* __restrict__ b_hh,
                          const __bf16* __restrict__ xtp, const __bf16* __restrict__ wihp,
                          __bf16* __restrict__ hbuf,
                          float* __restrict__ hlast, unsigned int* __restrict__ flags) {
  __shared__ __bf16 whh_lds[NT * KK_H * 512];   // 128 KB : [nt][kk][lane][j]
  __shared__ float  gstage[64 * 69];            // 17.3 KB, stride 69 (2-way max)
  __shared__ float  bias_lds[NC];

  const int tid = threadIdx.x;
  const int bid = blockIdx.x;
  // XCD swizzle: bid%8 = XCD. Group 0 -> XCDs 0-3, group 1 -> XCDs 4-7.
  const int r8  = bid & 7;
  const int p   = r8 >> 2;                     // batch group
  const int bIG = (bid >> 3) * 4 + (r8 & 3);   // [0,64) within group
  const int j0  = bIG * 16;                    // owned h-columns [j0, j0+16)

  // ---- one-time: pack W_hh slice (64 cols x 1024) into LDS in B-frag order ----
  for (int e = tid; e < NT * KK_H * 512; e += 256) {
    int j = e & 7, l = (e >> 3) & 63, kk = (e >> 9) & 31, nt = e >> 14;
    int col = nt * HH + j0 + (l & 15);         // gate=nt, jj=l&15
    int k = kk * 32 + ((l >> 4) << 3) + j;
    whh_lds[e] = (__bf16)W_hh[col * HH + k];
  }
  if (tid < NC) {
    int col = (tid >> 4) * HH + j0 + (tid & 15);
    bias_lds[tid] = b_ih[col] + b_hh[col];
  }
  __syncthreads();

  const int w = tid >> 6;    // wave id = M-tile
  const int l = tid & 63;
  unsigned int* gflags = flags + p * 128;
  const __bf16* wp = wihp + bIG * WIH_BLK;

  // cell state in registers: this thread owns (m = w*16 + (l>>2), jj = (l&3)*4+s)
  float creg[4] = {0.f, 0.f, 0.f, 0.f};

  for (int t = 0; t < SS; ++t) {
    const int rb = t & 1, wb = rb ^ 1;
    const __bf16* xb = xtp + (size_t)(t * 2 + p) * XTP_SLAB + w * (KK_X * 512);
    f32x4 acc[NT];
    #pragma unroll
    for (int nt = 0; nt < NT; ++nt) acc[nt] = (f32x4){0.f, 0.f, 0.f, 0.f};

    // x-part: K=288, independent of h_t -> before the poll (hidden under wait).
    // A from xtp (cached), B from wihp (cached, L2-resident 36 KB/block).
    #pragma unroll
    for (int kk = 0; kk < KK_X; ++kk) {
      bf16x8 a = *(const bf16x8*)(xb + kk * 512 + l * 8);
      #pragma unroll
      for (int nt = 0; nt < NT; ++nt) {
        bf16x8 b = *(const bf16x8*)(wp + (nt * KK_X + kk) * 512 + l * 8);
        acc[nt] = __builtin_amdgcn_mfma_f32_16x16x32_bf16(a, b, acc[nt], 0, 0, 0);
      }
    }

    // ---- barrier wait: all 64 group blocks published h_t (sc1 polls) ----
    if (t > 0) {
      if (tid < 64) {
        const unsigned int tgt = (unsigned int)t;
        for (;;) {
          unsigned int fa;
          asm volatile("global_load_dword %0, %1, off sc1\n\t"
                       "s_waitcnt vmcnt(0)"
                       : "=v"(fa) : "v"(gflags + tid));
          if (!__ballot(fa < tgt)) break;
          __builtin_amdgcn_s_sleep(1);
        }
      }
      __syncthreads();
    }

    // h-part: K=1024. A via sc1 loads from L3 (where producers deposited h),
    // pipelined 4 chunks x 8 dwordx4, partial vmcnt waits. B from LDS.
    {
      const __bf16* hbL = hbuf + (p * 2 + rb) * HBUF_SLAB + w * (KK_H * 512) + l * 8;
      u32x4 A0[8], A1[8];
      #pragma unroll
      for (int i = 0; i < 8; ++i) A0[i] = ldg_dev16(hbL + i * 512);
      #pragma unroll
      for (int i = 0; i < 8; ++i) A1[i] = ldg_dev16(hbL + (8 + i) * 512);

      CLAIMW("8", A0);
      #pragma unroll
      for (int i = 0; i < 8; ++i) {
        #pragma unroll
        for (int nt = 0; nt < NT; ++nt) {
          bf16x8 b = *(const bf16x8*)(whh_lds + (nt * KK_H + i) * 512 + l * 8);
          acc[nt] = __builtin_amdgcn_mfma_f32_16x16x32_bf16(asbf(A0[i]), b, acc[nt], 0, 0, 0);
        }
      }
      #pragma unroll
      for (int i = 0; i < 8; ++i) A0[i] = ldg_dev16(hbL + (16 + i) * 512);

      CLAIMW("8", A1);
      #pragma unroll
      for (int i = 0; i < 8; ++i) {
        int kk = 8 + i;
        #pragma unroll
        for (int nt = 0; nt < NT; ++nt) {
          bf16x8 b = *(const bf16x8*)(whh_lds + (nt * KK_H + kk) * 512 + l * 8);
          acc[nt] = __builtin_amdgcn_mfma_f32_16x16x32_bf16(asbf(A1[i]), b, acc[nt], 0, 0, 0);
        }
      }
      #pragma unroll
      for (int i = 0; i < 8; ++i) A1[i] = ldg_dev16(hbL + (24 + i) * 512);

      CLAIMW("8", A0);
      #pragma unroll
      for (int i = 0; i < 8; ++i) {
        int kk = 16 + i;
        #pragma unroll
        for (int nt = 0; nt < NT; ++nt) {
          bf16x8 b = *(const bf16x8*)(whh_lds + (nt * KK_H + kk) * 512 + l * 8);
          acc[nt] = __builtin_amdgcn_mfma_f32_16x16x32_bf16(asbf(A0[i]), b, acc[nt], 0, 0, 0);
        }
      }

      CLAIMW("0", A1);
      #pragma unroll
      for (int i = 0; i < 8; ++i) {
        int kk = 24 + i;
        #pragma unroll
        for (int nt = 0; nt < NT; ++nt) {
          bf16x8 b = *(const bf16x8*)(whh_lds + (nt * KK_H + kk) * 512 + l * 8);
          acc[nt] = __builtin_amdgcn_mfma_f32_16x16x32_bf16(asbf(A1[i]), b, acc[nt], 0, 0, 0);
        }
      }
    }

    // stage accumulators + bias to LDS (wave-local region: rows w*16..w*16+15)
    {
      int q = l >> 4, n16 = l & 15;
      #pragma unroll
      for (int nt = 0; nt < NT; ++nt) {
        float bi = bias_lds[nt * 16 + n16];
        #pragma unroll
        for (int rr = 0; rr < 4; ++rr) {
          int m = w * 16 + q * 4 + rr;
          gstage[m * 69 + nt * 16 + n16] = acc[nt][rr] + bi;
        }
      }
    }
    // cross-lane within wave only -> lgkmcnt drain suffices, no barrier
    asm volatile("s_waitcnt lgkmcnt(0)" ::: "memory");

    // gate phase (wave-local): thread -> (m = w*16 + (l>>2), jj = (l&3)*4 + s)
    {
      __bf16* hw = hbuf + (p * 2 + wb) * HBUF_SLAB;
      int mloc = l >> 2, m = w * 16 + mloc, jq = l & 3;
      float h4[4];
      #pragma unroll
      for (int s = 0; s < 4; ++s) {
        int jj = jq * 4 + s;
        float gi = gstage[m * 69 + jj];
        float gf = gstage[m * 69 + 16 + jj];
        float gg = gstage[m * 69 + 32 + jj];
        float go = gstage[m * 69 + 48 + jj];
        float i_ = sigmoid_f(gi);
        float f_ = sigmoid_f(gf);
        float g_ = tanh_f(gg);
        float o_ = sigmoid_f(go);
        float c  = f_ * creg[s] + i_ * g_;
        creg[s] = c;
        h4[s] = o_ * tanh_f(c);
      }
      union { __bf16 h[4]; u32x2 u; } pk;
      #pragma unroll
      for (int s = 0; s < 4; ++s) pk.h[s] = (__bf16)h4[s];
      int k0 = j0 + jq * 4;
      // A-frag offset for (m, k0..k0+3): same (kk,q2), j contiguous
      int off0 = ((w * 32 + (k0 >> 5)) * 64 + ((k0 >> 3) & 3) * 16 + mloc) * 8 + (k0 & 7);
      stg_dev8(hw + off0, pk.u);
      if (t == SS - 1) {
        f32x4 hv = {h4[0], h4[1], h4[2], h4[3]};
        *(f32x4*)(hlast + (p * MG + m) * HH + k0) = hv;
      }
    }

    // ---- signal: drain write-through h stores to L3, then release flag ----
    asm volatile("s_waitcnt vmcnt(0)" ::: "memory");
    __syncthreads();
    if (t < SS - 1 && tid == 0) {
      stg_dev4(gflags + bIG, (unsigned int)(t + 1));
    }
  }
}

__global__ void fc_kernel(const float* __restrict__ hlast, const float* __restrict__ W_fc,
                          const float* __restrict__ b_fc, float* __restrict__ out) {
  int b = blockIdx.x;            // 128
  int t = threadIdx.x;           // 256
  int o = t >> 2, part = t & 3;
  const float* hr = hlast + b * HH;
  const float* wr = W_fc + o * HH;
  float s = 0.f;
  #pragma unroll 4
  for (int k0 = part * 4; k0 < HH; k0 += 16) {
    float4 hv = *(const float4*)(hr + k0);
    float4 wv = *(const float4*)(wr + k0);
    s += hv.x * wv.x + hv.y * wv.y + hv.z * wv.z + hv.w * wv.w;
  }
  s += __shfl_xor(s, 1);
  s += __shfl_xor(s, 2);
  if (part == 0) out[b * OO + o] = s + b_fc[o];
}

extern "C" void kernel_launch(void* const* d_in, const int* in_sizes, int n_in,
                              void* d_out, int out_size, void* d_ws, size_t ws_size,
                              hipStream_t stream) {
  const float* x    = (const float*)d_in[0];
  const float* mask = (const float*)d_in[1];
  const float* ti   = (const float*)d_in[2];
  const float* W_ih = (const float*)d_in[3];
  const float* W_hh = (const float*)d_in[4];
  const float* b_ih = (const float*)d_in[5];
  const float* b_hh = (const float*)d_in[6];
  const float* W_fc = (const float*)d_in[7];
  const float* b_fc = (const float*)d_in[8];
  float* out = (float*)d_out;

  char* ws = (char*)d_ws;
  unsigned int* flags = (unsigned int*)ws;
  __bf16* hbuf  = (__bf16*)(ws + WS_HBUF);
  float*  hlast = (float*)(ws + WS_HLAST);
  __bf16* xtp   = (__bf16*)(ws + WS_XTP);
  __bf16* wihp  = (__bf16*)(ws + WS_WIHP);

  // zero flags + h double-buffers (ws poisoned 0xAA before each launch)
  hipMemsetAsync(ws, 0, WS_HLAST, stream);

  prepack_kernel<<<(1024 * XTP_SLAB) / 256, 256, 0, stream>>>(x, mask, ti, xtp);
  wih_prepack<<<(128 * WIH_BLK) / 256, 256, 0, stream>>>(W_ih, wihp);
  lstm_scan<<<NGROUP * GBLK, 256, 0, stream>>>(W_hh, b_ih, b_hh, xtp, wihp, hbuf, hlast, flags);
  fc_kernel<<<BB, 256, 0, stream>>>(hlast, W_fc, b_fc, out);
}

// Round 5
// 2425.502 us; speedup vs baseline: 1.6291x; 1.6291x over previous
//
#include <hip/hip_runtime.h>
#include <hip/hip_bf16.h>

typedef __bf16 bf16x8 __attribute__((ext_vector_type(8)));
typedef float f32x4 __attribute__((ext_vector_type(4)));
typedef unsigned int u32x4 __attribute__((ext_vector_type(4)));

#define BB   128
#define SS   512
#define DD   128
#define HH   1024
#define OO   64
#define IIN  257

// scan decomposition: 4 batch groups (32 rows) x 64 blocks; block owns 16 h-cols
// (64 gate cols = 4 gates x 16). 4 waves = 2 m-tiles x 2 K-halves (K-split).
#define NGROUP 4
#define GBLK   64
#define MG     32
#define KK_H   32     // 1024/32
#define KK_X   9      // 288/32

#define XTP_MT    (KK_X*512)      // 4608 bf16 per (t,p,mt)
#define HBUF_SLAB (2*KK_H*512)    // 32768 bf16 = 64 KB per (p,buf)
#define WIH_BLK   (4*KK_X*512)    // 18432 bf16 per q (shared by all 4 groups)
#define RSTRIDE   20              // padded m-stride in reduce LDS

// ws layout (bytes): [0,1024) flags (256 u32) | hbuf 8 slabs (512 KB)
// | hlast fp32 128x1024 (512 KB) | xtp (36.9 MB) | wihp (2.25 MB)
#define WS_HBUF  1024
#define WS_HLAST 525312
#define WS_XTP   1049600
#define WS_WIHP  38798336

// ---- device-scope (sc1) ops: bypass L1/L2, coherent at L3 (MALL). No
// buffer_wbl2/buffer_inv anywhere -> no cache-maintenance serialization.
__device__ __forceinline__ u32x4 ldg_dev16(const void* p) {
  u32x4 r;
  asm volatile("global_load_dwordx4 %0, %1, off sc1" : "=v"(r) : "v"(p));
  return r;
}
__device__ __forceinline__ void stg_dev4(void* p, unsigned int v) {
  asm volatile("global_store_dword %0, %1, off sc1" :: "v"(p), "v"(v));
}
__device__ __forceinline__ void stg_dev2(void* p, unsigned int v) {
  asm volatile("global_store_short %0, %1, off sc1" :: "v"(p), "v"(v));
}
__device__ __forceinline__ bf16x8 asbf(u32x4 v) {
  union { u32x4 u; bf16x8 h; } c; c.u = v; return c.h;
}

#define CLAIMW(CNTSTR, A)                                            \
  asm volatile("s_waitcnt vmcnt(" CNTSTR ")"                         \
    : "+v"((A)[0]), "+v"((A)[1]), "+v"((A)[2]), "+v"((A)[3]),        \
      "+v"((A)[4]), "+v"((A)[5]), "+v"((A)[6]), "+v"((A)[7]))

// xtp A-frags: idx = (((t*4+p)*2+mt)*9 + kk)*512 + l*8 + j
__global__ void prepack_kernel(const float* __restrict__ x, const float* __restrict__ mask,
                               const float* __restrict__ ti, __bf16* __restrict__ xtp) {
  int idx = blockIdx.x * 256 + threadIdx.x;        // 18,874,368 total
  int j = idx & 7, l = (idx >> 3) & 63;
  int rest = idx >> 9;
  int kk = rest % 9;
  int rest2 = rest / 9;
  int mt = rest2 & 1;
  int rest3 = rest2 >> 1;
  int p = rest3 & 3;
  int t = rest3 >> 2;
  int b = p * MG + mt * 16 + (l & 15);
  int k = kk * 32 + ((l >> 4) << 3) + j;
  float v;
  if (k < 128)       v = x[(b * SS + t) * DD + k];
  else if (k < 256)  v = mask[(b * SS + t) * DD + (k - 128)];
  else if (k == 256) v = ti[b * SS + t];
  else               v = 0.f;
  xtp[idx] = (__bf16)v;
}

// W_ih B-frags per col-slice q: [q][nt][kk][lane][8] (groups share q-slices)
__global__ void wih_prepack(const float* __restrict__ W_ih, __bf16* __restrict__ wihp) {
  int idx = blockIdx.x * 256 + threadIdx.x;        // 64*18432 = 1,179,648
  int j = idx & 7, l = (idx >> 3) & 63;
  int rest = idx >> 9;
  int kk = rest % 9;
  int rest2 = rest / 9;
  int nt = rest2 & 3, q = rest2 >> 2;
  int col = nt * HH + q * 16 + (l & 15);
  int k = kk * 32 + ((l >> 4) << 3) + j;
  wihp[idx] = (k < IIN) ? (__bf16)W_ih[col * IIN + k] : (__bf16)0.f;
}

__device__ __forceinline__ float sigmoid_f(float v) { return 1.f / (1.f + __expf(-v)); }
__device__ __forceinline__ float tanh_f(float v)    { return 1.f - 2.f / (__expf(2.f * v) + 1.f); }

__launch_bounds__(256, 1)
__global__ void lstm_scan(const float* __restrict__ W_hh,
                          const float* __restrict__ b_ih, const float* __restrict__ b_hh,
                          const __bf16* __restrict__ xtp, const __bf16* __restrict__ wihp,
                          __bf16* __restrict__ hbuf,
                          float* __restrict__ hlast, unsigned int* __restrict__ flags) {
  __shared__ __bf16 whh_lds[4 * KK_H * 512];      // 128 KB: [nt][kk][lane][j]
  __shared__ float  red_lds[2 * 4 * 16 * RSTRIDE]; // 10 KB K-split reduce buffer

  const int tid = threadIdx.x;
  const int bid = blockIdx.x;
  // group p -> XCD pair {2p,2p+1}; q = block's col slice within group
  const int p = (bid & 7) >> 1;
  const int q = (bid >> 3) * 2 + (bid & 1);    // [0,64)
  const int j0 = q * 16;                       // owned h-cols [j0, j0+16)

  // ---- one-time: pack W_hh slice (4 gates x 16 cols x 1024 K) in B-frag order ----
  for (int e = tid; e < 4 * KK_H * 512; e += 256) {
    int j = e & 7, l = (e >> 3) & 63, kk = (e >> 9) & 31, nt = e >> 14;
    int col = nt * HH + j0 + (l & 15);
    int k = kk * 32 + ((l >> 4) << 3) + j;
    whh_lds[e] = (__bf16)W_hh[col * HH + k];
  }
  __syncthreads();

  const int w = tid >> 6, l = tid & 63;
  const int mt = w & 1;          // m-tile (16 rows)
  const int kh = w >> 1;         // K-half
  unsigned int* gflags = flags + p * 64;
  const __bf16* wp = wihp + q * WIH_BLK;

  // bias in registers (used by kh==0 threads in gate phase)
  float bias_r[4];
  #pragma unroll
  for (int nt = 0; nt < 4; ++nt)
    bias_r[nt] = b_ih[nt * HH + j0 + (l & 15)] + b_hh[nt * HH + j0 + (l & 15)];
  // cell state in registers: (m = mt*16 + (l>>4)*4 + r, col = j0 + (l&15))
  float creg[4] = {0.f, 0.f, 0.f, 0.f};

  const int kkh0 = kh * 16;      // this wave's K-half of the h-part

  for (int t = 0; t < SS; ++t) {
    const int rb = t & 1, wb = rb ^ 1;
    f32x4 acc[4];
    #pragma unroll
    for (int nt = 0; nt < 4; ++nt) acc[nt] = (f32x4){0.f, 0.f, 0.f, 0.f};

    // x-part (K=288 split 128/160 across K-halves), pre-poll, cached loads
    {
      const __bf16* xb = xtp + ((size_t)((t * 4 + p) * 2 + mt)) * XTP_MT + l * 8;
      if (kh == 0) {
        #pragma unroll
        for (int kk = 0; kk < 4; ++kk) {
          bf16x8 a = *(const bf16x8*)(xb + kk * 512);
          #pragma unroll
          for (int nt = 0; nt < 4; ++nt) {
            bf16x8 b = *(const bf16x8*)(wp + (nt * KK_X + kk) * 512 + l * 8);
            acc[nt] = __builtin_amdgcn_mfma_f32_16x16x32_bf16(a, b, acc[nt], 0, 0, 0);
          }
        }
      } else {
        #pragma unroll
        for (int kk = 4; kk < 9; ++kk) {
          bf16x8 a = *(const bf16x8*)(xb + kk * 512);
          #pragma unroll
          for (int nt = 0; nt < 4; ++nt) {
            bf16x8 b = *(const bf16x8*)(wp + (nt * KK_X + kk) * 512 + l * 8);
            acc[nt] = __builtin_amdgcn_mfma_f32_16x16x32_bf16(a, b, acc[nt], 0, 0, 0);
          }
        }
      }
    }

    // ---- barrier wait: all 64 group blocks published h_t (sc1 polls) ----
    if (t > 0) {
      if (tid < 64) {
        const unsigned int tgt = (unsigned int)t;
        for (;;) {
          unsigned int fa;
          asm volatile("global_load_dword %0, %1, off sc1\n\t"
                       "s_waitcnt vmcnt(0)"
                       : "=v"(fa) : "v"(gflags + tid));
          if (!__ballot(fa < tgt)) break;
          __builtin_amdgcn_s_sleep(1);
        }
      }
      __syncthreads();
    }

    // h-part: this wave's K-half (16 ksteps). A via sc1 from L3, B from LDS.
    {
      const __bf16* hbL = hbuf + (p * 2 + rb) * HBUF_SLAB + (mt * KK_H + kkh0) * 512 + l * 8;
      u32x4 A0[8], A1[8];
      #pragma unroll
      for (int i = 0; i < 8; ++i) A0[i] = ldg_dev16(hbL + i * 512);
      #pragma unroll
      for (int i = 0; i < 8; ++i) A1[i] = ldg_dev16(hbL + (8 + i) * 512);

      CLAIMW("8", A0);
      #pragma unroll
      for (int i = 0; i < 8; ++i) {
        int kk = kkh0 + i;
        #pragma unroll
        for (int nt = 0; nt < 4; ++nt) {
          bf16x8 b = *(const bf16x8*)(whh_lds + (nt * KK_H + kk) * 512 + l * 8);
          acc[nt] = __builtin_amdgcn_mfma_f32_16x16x32_bf16(asbf(A0[i]), b, acc[nt], 0, 0, 0);
        }
      }
      CLAIMW("0", A1);
      #pragma unroll
      for (int i = 0; i < 8; ++i) {
        int kk = kkh0 + 8 + i;
        #pragma unroll
        for (int nt = 0; nt < 4; ++nt) {
          bf16x8 b = *(const bf16x8*)(whh_lds + (nt * KK_H + kk) * 512 + l * 8);
          acc[nt] = __builtin_amdgcn_mfma_f32_16x16x32_bf16(asbf(A1[i]), b, acc[nt], 0, 0, 0);
        }
      }
    }

    // ---- K-split reduction: kh1 deposits partials, kh0 accumulates ----
    {
      const int rbase = ((mt * 4) * 16 + (l & 15)) * RSTRIDE + ((l >> 4) << 2);
      if (kh == 1) {
        #pragma unroll
        for (int nt = 0; nt < 4; ++nt)
          *(f32x4*)(red_lds + rbase + nt * 16 * RSTRIDE) = acc[nt];
      }
      __syncthreads();
      if (kh == 0) {
        #pragma unroll
        for (int nt = 0; nt < 4; ++nt)
          acc[nt] += *(const f32x4*)(red_lds + rbase + nt * 16 * RSTRIDE);
      }
    }

    // ---- gate phase: entirely in kh0 registers (C-layout col = l&15 = own col) ----
    if (kh == 0) {
      __bf16* hw = hbuf + (p * 2 + wb) * HBUF_SLAB;
      const int c = j0 + (l & 15);                  // own h-col
      const int kkp = c >> 5, gsub = (c >> 3) & 3, jp = c & 7;
      const int lane0 = gsub * 16 + ((l >> 4) << 2);
      const int offb = ((mt * 32 + kkp) * 64 + lane0) * 8 + jp;
      #pragma unroll
      for (int r = 0; r < 4; ++r) {
        float i_ = sigmoid_f(acc[0][r] + bias_r[0]);
        float f_ = sigmoid_f(acc[1][r] + bias_r[1]);
        float g_ = tanh_f(acc[2][r] + bias_r[2]);
        float o_ = sigmoid_f(acc[3][r] + bias_r[3]);
        float cc = f_ * creg[r] + i_ * g_;
        creg[r] = cc;
        float h = o_ * tanh_f(cc);
        union { __bf16 b; unsigned short u; } cv; cv.b = (__bf16)h;
        stg_dev2(hw + offb + r * 8, (unsigned int)cv.u);
        if (t == SS - 1)
          hlast[(p * MG + mt * 16 + ((l >> 4) << 2) + r) * HH + c] = h;
      }
    }

    // ---- signal: drain h stores to L3, then release own flag ----
    asm volatile("s_waitcnt vmcnt(0)" ::: "memory");
    __syncthreads();
    if (t < SS - 1 && tid == 0) {
      stg_dev4(gflags + q, (unsigned int)(t + 1));
    }
  }
}

__global__ void fc_kernel(const float* __restrict__ hlast, const float* __restrict__ W_fc,
                          const float* __restrict__ b_fc, float* __restrict__ out) {
  int b = blockIdx.x;            // 128
  int t = threadIdx.x;           // 256
  int o = t >> 2, part = t & 3;
  const float* hr = hlast + b * HH;
  const float* wr = W_fc + o * HH;
  float s = 0.f;
  #pragma unroll 4
  for (int k0 = part * 4; k0 < HH; k0 += 16) {
    float4 hv = *(const float4*)(hr + k0);
    float4 wv = *(const float4*)(wr + k0);
    s += hv.x * wv.x + hv.y * wv.y + hv.z * wv.z + hv.w * wv.w;
  }
  s += __shfl_xor(s, 1);
  s += __shfl_xor(s, 2);
  if (part == 0) out[b * OO + o] = s + b_fc[o];
}

extern "C" void kernel_launch(void* const* d_in, const int* in_sizes, int n_in,
                              void* d_out, int out_size, void* d_ws, size_t ws_size,
                              hipStream_t stream) {
  const float* x    = (const float*)d_in[0];
  const float* mask = (const float*)d_in[1];
  const float* ti   = (const float*)d_in[2];
  const float* W_ih = (const float*)d_in[3];
  const float* W_hh = (const float*)d_in[4];
  const float* b_ih = (const float*)d_in[5];
  const float* b_hh = (const float*)d_in[6];
  const float* W_fc = (const float*)d_in[7];
  const float* b_fc = (const float*)d_in[8];
  float* out = (float*)d_out;

  char* ws = (char*)d_ws;
  unsigned int* flags = (unsigned int*)ws;
  __bf16* hbuf  = (__bf16*)(ws + WS_HBUF);
  float*  hlast = (float*)(ws + WS_HLAST);
  __bf16* xtp   = (__bf16*)(ws + WS_XTP);
  __bf16* wihp  = (__bf16*)(ws + WS_WIHP);

  // zero flags + h double-buffers (ws poisoned 0xAA before each launch)
  hipMemsetAsync(ws, 0, WS_HLAST, stream);

  prepack_kernel<<<(SS * NGROUP * 2 * XTP_MT) / 256, 256, 0, stream>>>(x, mask, ti, xtp);
  wih_prepack<<<(64 * WIH_BLK) / 256, 256, 0, stream>>>(W_ih, wihp);
  lstm_scan<<<NGROUP * GBLK, 256, 0, stream>>>(W_hh, b_ih, b_hh, xtp, wihp, hbuf, hlast, flags);
  fc_kernel<<<BB, 256, 0, stream>>>(hlast, W_fc, b_fc, out);
}